// Round 2
// baseline (412.709 us; speedup 1.0000x reference)
//
#include <hip/hip_runtime.h>

// Problem constants (from reference setup_inputs): B=2, H=W=128.
#define B_ITEMS 2
#define W_IMG   128
#define N_PTS   16384          // H*W
#define QS      4              // col-quarters per 64-row group
#define CH_GRID 4096           // max Utot = 4 s * 256 rowgroups * QS
#define BIGF    3.4e38f

// ---------------------------------------------------------------------------
// Kernel 1: compaction (R7 structure, proven). Also inits the rmG min table
// (65536 slots == 256 blocks x 256 threads) and zeroes out[0].
//   raw[pos] = (x, y, z, |q|^2)        row side
//   tf [pos] = (-2x, -2y, -2z, |q|^2)  col side: d = |p|^2 + fma3(p, tf)
// ---------------------------------------------------------------------------
__global__ __launch_bounds__(256) void prep_kernel(
        const float* __restrict__ pred,
        const float* __restrict__ gt,
        const int*   __restrict__ mask,
        const float* fxp, const float* fyp,
        const float* cxp, const float* cyp,
        int*    __restrict__ cnt,       // [0]=np0 [1]=np1 [2]=ng0 [3]=ng1
        float4* __restrict__ pR, float4* __restrict__ gR,   // raw   [B][N]
        float4* __restrict__ pT, float4* __restrict__ gT,   // transf[B][N]
        float*  __restrict__ rmG,       // [4][N_PTS] per-row min table
        float*  __restrict__ out) {
    int s    = blockIdx.x >> 6;
    int b    = s & 1;
    int isG  = s >> 1;
    int tid  = threadIdx.x;
    int idx  = (blockIdx.x & 63) * 256 + tid;
    int lane = tid & 63, w = tid >> 6;

    if (blockIdx.x == 0 && tid == 0) out[0] = 0.0f;
    rmG[(blockIdx.x << 8) + tid] = BIGF;

    float x, y, z;
    if (!isG) {
        float fx = *fxp, fy = *fyp, cx = *cxp, cy = *cyp;
        float u = (float)(idx & (W_IMG - 1));
        float v = (float)(idx >> 7);
        z = pred[b * N_PTS + idx];
        x = (u - cx) / fx * z;
        y = (v - cy) / fy * z;
    } else {
        x = gt[(b * 3 + 0) * N_PTS + idx];
        y = gt[(b * 3 + 1) * N_PTS + idx];
        z = gt[(b * 3 + 2) * N_PTS + idx];
    }
    int  mv = mask[b * N_PTS + idx];
    bool ok = (mv > 0) && (((x + y) + z) != 0.0f);

    unsigned long long bal = __ballot(ok);
    int nw  = __popcll(bal);
    int pre = __popcll(bal & ((1ull << lane) - 1ull));

    __shared__ int wbase[4];
    __shared__ int blockbase;
    if (lane == 0) wbase[w] = nw;
    __syncthreads();
    if (tid == 0) {
        int s0 = 0;
#pragma unroll
        for (int i = 0; i < 4; ++i) { int t = wbase[i]; wbase[i] = s0; s0 += t; }
        blockbase = s0 ? atomicAdd(&cnt[s], s0) : 0;
    }
    __syncthreads();

    if (ok) {
        int pos = blockbase + wbase[w] + pre;
        float ps = fmaf(z, z, fmaf(y, y, x * x));
        float4* __restrict__ raw = (isG ? gR : pR) + b * N_PTS;
        float4* __restrict__ tf  = (isG ? gT : pT) + b * N_PTS;
        raw[pos] = make_float4(x, y, z, ps);
        tf[pos]  = make_float4(-2.0f * x, -2.0f * y, -2.0f * z, ps);
    }
}

// ---------------------------------------------------------------------------
// Kernel 2 (R12 rewrite): scalar-broadcast chamfer, NO LDS staging, NO
// barriers in the hot loop.
//  - lanes = rows: lane l owns row rowbase+l; B-cols are wave-uniform ->
//    loaded as uniform float4 (compiler emits s_load into SGPRs; wave id
//    forced uniform via readfirstlane so uniformity analysis can't miss).
//  - inner loop: per 2 cols = 6 v_fma + 1 v_min3 (3.5 VALU/pair, floor
//    ~12 us), SMEM on the scalar pipe in parallel, zero LDS/barrier cost.
//    R1 lesson: the LDS-staged structure was barrier/LDS-pipe bound, which
//    is why 2->4 waves/SIMD was neutral; this removes that structure.
//  - block = 64 rows x col-quarter; 4 waves sub-split the quarter ->
//    ~2048 active blocks = 8 blocks/CU = 8 waves/SIMD (VGPR<=64: B is in
//    SGPRs, ~25 VGPR). End: 1 KB LDS combine of the 4 wave-mins,
//    atomicMin into rmG (64/block, proven R1 path).
//  - finish FUSED via done-counter: last of the 4096 blocks reduces rmG
//    (agent-scope atomic loads -> same coherent point as the atomicMins)
//    and stores out[0]. Removes the separate finish dispatch + gap.
// ---------------------------------------------------------------------------
__global__ __launch_bounds__(256, 8) void chamfer_kernel(
        const int*    __restrict__ cnt,
        const float4* __restrict__ pR, const float4* __restrict__ gR,
        const float4* __restrict__ pT, const float4* __restrict__ gT,
        float* __restrict__ rmG,
        int*   __restrict__ done,
        float* __restrict__ out) {
    int np0 = cnt[0], np1 = cnt[1], ng0 = cnt[2], ng1 = cnt[3];
    int naArr[4] = {np0, ng0, np1, ng1};
    int nbArr[4] = {ng0, np0, ng1, np1};
    const float4* Arow[4] = {pR, gR, pR + N_PTS, gR + N_PTS};
    const float4* Bcol[4] = {gT, pT, gT + N_PTS, pT + N_PTS};

    int units[4];
    int Utot = 0;
#pragma unroll
    for (int i = 0; i < 4; ++i) {
        units[i] = (naArr[i] > 0 && nbArr[i] > 0) ? (((naArr[i] + 63) >> 6) * QS) : 0;
        Utot += units[i];
    }

    int tid  = threadIdx.x;
    int lane = tid & 63;
    int w    = __builtin_amdgcn_readfirstlane(tid >> 6);   // wave id, SGPR

    __shared__ float sm[4][64];
    __shared__ float wsum[4];
    __shared__ int   lastFlag;

    int u = blockIdx.x;
    if (u < Utot) {
        int s = 0;
        while (u >= units[s]) { u -= units[s]; ++s; }
        int na = naArr[s], nb = nbArr[s];
        const float4* __restrict__ A  = Arow[s];
        const float4* __restrict__ Bp = Bcol[s];
        int q       = u & (QS - 1);
        int rowbase = (u >> 2) * 64;

        int Lq  = (nb + QS - 1) >> 2;        // quarter length
        int cb0 = q * Lq;
        int cc  = min(nb - cb0, Lq); if (cc < 0) cc = 0;
        int Lw  = (cc + 3) >> 2;             // per-wave length
        int wb  = cb0 + w * Lw;
        int wc  = min(cc - w * Lw, Lw); if (wc < 0) wc = 0;

        int    row = rowbase + lane;         // <= 16383 always (capacity ok;
        float4 av  = A[row];                 // poison rows finite, gated later)
        float  px = av.x, py = av.y, pz = av.z, ps = av.w;
        float  rm = BIGF;

        const float4* __restrict__ Bq = Bp + wb;

#define CHPAIR(CA, CB) { \
        float d0_ = fmaf(px, CA.x, fmaf(py, CA.y, fmaf(pz, CA.z, CA.w))); \
        float d1_ = fmaf(px, CB.x, fmaf(py, CB.y, fmaf(pz, CB.z, CB.w))); \
        rm = fminf(fminf(rm, d0_), d1_); }

        int j = 0;
#pragma unroll 1
        for (; j + 8 <= wc; j += 8) {        // 8 uniform cols -> 32 SGPRs
            float4 c0 = Bq[j + 0], c1 = Bq[j + 1];
            float4 c2 = Bq[j + 2], c3 = Bq[j + 3];
            float4 c4 = Bq[j + 4], c5 = Bq[j + 5];
            float4 c6 = Bq[j + 6], c7 = Bq[j + 7];
            CHPAIR(c0, c1)
            CHPAIR(c2, c3)
            CHPAIR(c4, c5)
            CHPAIR(c6, c7)
        }
        for (; j < wc; ++j) {                // ragged tail, uniform branch
            float4 c = Bq[j];
            float d = fmaf(px, c.x, fmaf(py, c.y, fmaf(pz, c.z, c.w)));
            rm = fminf(rm, d);
        }
#undef CHPAIR

        sm[w][lane] = rm;                    // 2-way bank alias: free
        __syncthreads();
        if (tid < 64) {                      // lane==tid, w==0 -> ps matches row
            float m = fminf(fminf(sm[0][tid], sm[1][tid]),
                            fminf(sm[2][tid], sm[3][tid]));
            int r2 = rowbase + tid;
            if (r2 < na) {
                float vr = fmaxf(m + ps, 0.0f);      // nonneg -> int order ok
                atomicMin((int*)&rmG[(s << 14) + r2], __float_as_int(vr));
            }
        }
    }

    // -------- done-counter: last block (of all CH_GRID) does the final sum.
    __syncthreads();                         // drain this block's atomicMins
    __threadfence();
    if (tid == 0) {
        int old = atomicAdd(done, 1);
        lastFlag = (old == (int)gridDim.x - 1) ? 1 : 0;
    }
    __syncthreads();

    if (lastFlag) {                          // block-uniform branch
        int* rmGi = (int*)rmG;
        float acc = 0.0f;
#pragma unroll 1
        for (int s2 = 0; s2 < 4; ++s2) {
            if (nbArr[s2] <= 0) continue;    // no partner side -> contributes 0
            int na2  = naArr[s2];
            int base = s2 << 14;
            for (int k = tid; k < na2; k += 256)   // compacted prefix only
                acc += __int_as_float(__hip_atomic_load(&rmGi[base + k],
                        __ATOMIC_RELAXED, __HIP_MEMORY_SCOPE_AGENT));
        }
#pragma unroll
        for (int off = 32; off > 0; off >>= 1)
            acc += __shfl_down(acc, off, 64);
        if (lane == 0) wsum[w] = acc;
        __syncthreads();
        if (tid == 0)
            out[0] = (wsum[0] + wsum[1] + wsum[2] + wsum[3]) * (1.0f / B_ITEMS);
    }
}

extern "C" void kernel_launch(void* const* d_in, const int* in_sizes, int n_in,
                              void* d_out, int out_size, void* d_ws, size_t ws_size,
                              hipStream_t stream) {
    const float* pred = (const float*)d_in[0];
    const float* gt   = (const float*)d_in[1];
    const int*   mask = (const int*)  d_in[2];
    const float* fx   = (const float*)d_in[3];
    const float* fy   = (const float*)d_in[4];
    const float* cx   = (const float*)d_in[5];
    const float* cy   = (const float*)d_in[6];
    float* out = (float*)d_out;

    // ws: [0,256) cnt+done | pR 512K | gR 512K | pT 512K | gT 512K | rmG 256K
    char* ws = (char*)d_ws;
    size_t SEG = (size_t)B_ITEMS * N_PTS * 16;
    int*    cnt  = (int*)ws;
    int*    done = cnt + 4;
    float4* pR   = (float4*)(ws + 256);
    float4* gR   = (float4*)(ws + 256 + SEG);
    float4* pT   = (float4*)(ws + 256 + 2 * SEG);
    float4* gT   = (float4*)(ws + 256 + 3 * SEG);
    float*  rmG  = (float*) (ws + 256 + 4 * SEG);

    hipMemsetAsync(cnt, 0, 32, stream);      // cnt[0..3] + done

    prep_kernel<<<dim3(256), 256, 0, stream>>>(
        pred, gt, mask, fx, fy, cx, cy, cnt, pR, gR, pT, gT, rmG, out);

    chamfer_kernel<<<dim3(CH_GRID), 256, 0, stream>>>(
        cnt, pR, gR, pT, gT, rmG, done, out);
}

// Round 4
// 235.550 us; speedup vs baseline: 1.7521x; 1.7521x over previous
//
#include <hip/hip_runtime.h>

// Problem constants (from reference setup_inputs): B=2, H=W=128.
#define B_ITEMS 2
#define W_IMG   128
#define N_PTS   16384          // H*W
#define QS      2              // col-split across blocks
#define CH_GRID 2048           // max Utot = 4 s * 256 rowgroups * QS
#define BIGF    3.4e38f

// ---------------------------------------------------------------------------
// Kernel 1: compaction (R7 structure, proven). Also inits the rmG min table
// (65536 slots == 256 blocks x 256 threads) and zeroes out[0].
//   raw[pos] = (x, y, z, |q|^2)        row side
//   tf [pos] = (-2x, -2y, -2z, |q|^2)  col side: d = |p|^2 + fma3(p, tf)
// ---------------------------------------------------------------------------
__global__ __launch_bounds__(256) void prep_kernel(
        const float* __restrict__ pred,
        const float* __restrict__ gt,
        const int*   __restrict__ mask,
        const float* fxp, const float* fyp,
        const float* cxp, const float* cyp,
        int*    __restrict__ cnt,       // [0]=np0 [1]=np1 [2]=ng0 [3]=ng1
        float4* __restrict__ pR, float4* __restrict__ gR,   // raw   [B][N]
        float4* __restrict__ pT, float4* __restrict__ gT,   // transf[B][N]
        float*  __restrict__ rmG,       // [4][N_PTS] per-row min table
        float*  __restrict__ out) {
    int s    = blockIdx.x >> 6;
    int b    = s & 1;
    int isG  = s >> 1;
    int tid  = threadIdx.x;
    int idx  = (blockIdx.x & 63) * 256 + tid;
    int lane = tid & 63, w = tid >> 6;

    if (blockIdx.x == 0 && tid == 0) out[0] = 0.0f;
    rmG[(blockIdx.x << 8) + tid] = BIGF;

    float x, y, z;
    if (!isG) {
        float fx = *fxp, fy = *fyp, cx = *cxp, cy = *cyp;
        float u = (float)(idx & (W_IMG - 1));
        float v = (float)(idx >> 7);
        z = pred[b * N_PTS + idx];
        x = (u - cx) / fx * z;
        y = (v - cy) / fy * z;
    } else {
        x = gt[(b * 3 + 0) * N_PTS + idx];
        y = gt[(b * 3 + 1) * N_PTS + idx];
        z = gt[(b * 3 + 2) * N_PTS + idx];
    }
    int  mv = mask[b * N_PTS + idx];
    bool ok = (mv > 0) && (((x + y) + z) != 0.0f);

    unsigned long long bal = __ballot(ok);
    int nw  = __popcll(bal);
    int pre = __popcll(bal & ((1ull << lane) - 1ull));

    __shared__ int wbase[4];
    __shared__ int blockbase;
    if (lane == 0) wbase[w] = nw;
    __syncthreads();
    if (tid == 0) {
        int s0 = 0;
#pragma unroll
        for (int i = 0; i < 4; ++i) { int t = wbase[i]; wbase[i] = s0; s0 += t; }
        blockbase = s0 ? atomicAdd(&cnt[s], s0) : 0;
    }
    __syncthreads();

    if (ok) {
        int pos = blockbase + wbase[w] + pre;
        float ps = fmaf(z, z, fmaf(y, y, x * x));
        float4* __restrict__ raw = (isG ? gR : pR) + b * N_PTS;
        float4* __restrict__ tf  = (isG ? gT : pT) + b * N_PTS;
        raw[pos] = make_float4(x, y, z, ps);
        tf[pos]  = make_float4(-2.0f * x, -2.0f * y, -2.0f * z, ps);
    }
}

// ---------------------------------------------------------------------------
// Kernel 2 (R14): wave-private LDS chamfer, staging-size bug FIXED.
// R3 bug: wave tile was 256 float4 but a 64-lane wave staged only 64 ->
// 192 garbage entries. Fix: tile = 64 float4 = exactly 1 float4/lane.
// Layout rebalance: tc=lane&15 (16 parallel cols), tr=lane>>4, 16 rows/
// thread. Per 2 cols: 2 ds_read_b128 + 112 VALU inst -> LDS pipe ~43%
// (vs 86% at 8 rows/thread) — VALU-dominant. VGPR ~90 (<128) keeps
// 16 waves/CU. R11's "16 rows starves VGPRs" was the block-staged
// structure with big arrays; wave-private has no such arrays.
//  - block = 64 rows x col-half (QS=2); 2048 blocks = ~8/CU schedulable,
//    4 resident (VGPR), 4 waves/SIMD.
//  - wave owns cc/4 cols with its OWN dbuf (2x64 float4, 8 KB/block
//    total): hand-off is same-wave only -> in-order per-wave LDS pipe,
//    NO s_barrier in the hot loop. (R2 lesson: scalar cache serializes;
//    broadcast data belongs in LDS. R0/R1 lesson: cross-wave barrier
//    drain was the overhead above the VALU floor.)
//  - inner: 2 cols/iter (fmin3), 16 rows -> 3.5 VALU ops/pair, floor 12us.
//  - combine: 4 shfl_xor (tc fold) -> sm[w][row] -> ONE barrier -> 4-way
//    min -> atomicMin into rmG (int-order on nonneg floats; proven R1/R2).
//  - finish fused via done-counter (proven R2): last block sums rmG prefix.
// ---------------------------------------------------------------------------
__global__ __launch_bounds__(256, 4) void chamfer_kernel(
        const int*    __restrict__ cnt,
        const float4* __restrict__ pR, const float4* __restrict__ gR,
        const float4* __restrict__ pT, const float4* __restrict__ gT,
        float* __restrict__ rmG,
        int*   __restrict__ done,
        float* __restrict__ out) {
    int np0 = cnt[0], np1 = cnt[1], ng0 = cnt[2], ng1 = cnt[3];
    int naArr[4] = {np0, ng0, np1, ng1};
    int nbArr[4] = {ng0, np0, ng1, np1};
    const float4* Arow[4] = {pR, gR, pR + N_PTS, gR + N_PTS};
    const float4* Bcol[4] = {gT, pT, gT + N_PTS, pT + N_PTS};

    int units[4];
    int Utot = 0;
#pragma unroll
    for (int i = 0; i < 4; ++i) {
        units[i] = (naArr[i] > 0 && nbArr[i] > 0) ? (((naArr[i] + 63) >> 6) * QS) : 0;
        Utot += units[i];
    }

    int tid  = threadIdx.x;
    int lane = tid & 63;
    int w    = __builtin_amdgcn_readfirstlane(tid >> 6);   // wave id, SGPR

    __shared__ float4 sB[4][2][64];          // per-wave dbuf tiles (8 KB)
    __shared__ float  sm[4][64];
    __shared__ float  wsum[4];
    __shared__ int    lastFlag;

    int u = blockIdx.x;
    if (u < Utot) {
        int s = 0;
        while (u >= units[s]) { u -= units[s]; ++s; }
        int na = naArr[s], nb = nbArr[s];
        const float4* __restrict__ A  = Arow[s];
        const float4* __restrict__ Bp = Bcol[s];
        int q       = u & (QS - 1);
        int rowbase = (u >> 1) * 64;

        int Lq  = (nb + QS - 1) / QS;        // per-block col range
        int cb0 = q * Lq;
        int cc  = min(nb - cb0, Lq); if (cc < 0) cc = 0;
        int Lw  = (cc + 3) >> 2;             // per-wave col range
        int wb  = cb0 + w * Lw;
        int wc  = min(cc - w * Lw, Lw); if (wc < 0) wc = 0;

        int tc = lane & 15, tr = lane >> 4;

        // 16 rows/thread: row = rowbase + a*4 + tr (<= 16383 always; rows
        // >= na read finite ws poison, gated at the atomicMin).
        float px[16], py[16], pz[16], rm[16];
#pragma unroll
        for (int a = 0; a < 16; ++a) {
            float4 v = A[rowbase + a * 4 + tr];
            px[a] = v.x; py[a] = v.y; pz[a] = v.z;
            rm[a] = BIGF;
        }

        const float4* __restrict__ Bq = Bp + wb;
        float4 (* __restrict__ sBw)[64] = sB[w];
        int ntiles = (wc + 63) >> 6;         // 64-col tiles; can be 0

        // tile = 64 cols = exactly ONE float4 per lane (the R3 fix)
#define LOADTILE(T, DST) { \
        int j_ = (T) * 64 + lane; \
        if (((T) + 1) * 64 <= wc) { DST = Bq[j_]; } \
        else { \
            float4 v_ = Bp[min(wb + j_, N_PTS - 1)]; \
            bool ok_ = j_ < wc; \
            DST.x = ok_ ? v_.x : 0.0f; DST.y = ok_ ? v_.y : 0.0f; \
            DST.z = ok_ ? v_.z : 0.0f; DST.w = ok_ ? v_.w : BIGF; } }

        if (ntiles > 0) {
            float4 r0;
            LOADTILE(0, r0)
            sBw[0][lane] = r0;
            for (int t = 0; t < ntiles; ++t) {
                float4 r;                    // prefetch tile t+1 (global)
                bool have = (t + 1 < ntiles);
                if (have) { LOADTILE(t + 1, r) }
                const float4* __restrict__ bufp = &sBw[t & 1][tc];
#pragma unroll
                for (int k = 0; k < 4; k += 2) {
                    float4 c0 = bufp[k * 16];        // 16-lane bcast, 32 banks
                    float4 c1 = bufp[k * 16 + 16];
#pragma unroll
                    for (int a = 0; a < 16; ++a) {
                        float d0 = fmaf(px[a], c0.x,
                                     fmaf(py[a], c0.y, fmaf(pz[a], c0.z, c0.w)));
                        float d1 = fmaf(px[a], c1.x,
                                     fmaf(py[a], c1.y, fmaf(pz[a], c1.z, c1.w)));
                        rm[a] = fminf(fminf(rm[a], d0), d1);  // v_min3_f32
                    }
                }
                if (have) sBw[(t + 1) & 1][lane] = r;
                // no barrier: same-wave LDS ops are in-order; buffer is
                // wave-private so no cross-wave hazard exists.
            }
        }
#undef LOADTILE

        // fold over tc (lane bits 0..3): lanes sharing (tr,a) share a row
#pragma unroll
        for (int a = 0; a < 16; ++a) {
            float v = rm[a];
            v = fminf(v, __shfl_xor(v, 1, 64));
            v = fminf(v, __shfl_xor(v, 2, 64));
            v = fminf(v, __shfl_xor(v, 4, 64));
            v = fminf(v, __shfl_xor(v, 8, 64));
            rm[a] = v;
        }
        if (tc == 0) {
#pragma unroll
            for (int a = 0; a < 16; ++a) sm[w][a * 4 + tr] = rm[a];
        }
        __syncthreads();                     // the ONE barrier (wave combine)
        if (tid < 64) {
            float m = fminf(fminf(sm[0][tid], sm[1][tid]),
                            fminf(sm[2][tid], sm[3][tid]));
            int r2 = rowbase + tid;
            if (r2 < na) {
                float psv = A[r2].w;         // |p|^2 (L1-hot reload)
                float vr  = fmaxf(m + psv, 0.0f);    // nonneg -> int order ok
                atomicMin((int*)&rmG[(s << 14) + r2], __float_as_int(vr));
            }
        }
    }

    // -------- done-counter: last block (of all CH_GRID) does the final sum.
    __syncthreads();                         // block-uniform path
    __threadfence();
    if (tid == 0) {
        int old = atomicAdd(done, 1);
        lastFlag = (old == (int)gridDim.x - 1) ? 1 : 0;
    }
    __syncthreads();

    if (lastFlag) {                          // block-uniform branch
        int* rmGi = (int*)rmG;
        float acc = 0.0f;
#pragma unroll 1
        for (int s2 = 0; s2 < 4; ++s2) {
            if (nbArr[s2] <= 0) continue;    // no partner side -> contributes 0
            int na2  = naArr[s2];
            int base = s2 << 14;
            for (int k = tid; k < na2; k += 256)   // compacted prefix only
                acc += __int_as_float(__hip_atomic_load(&rmGi[base + k],
                        __ATOMIC_RELAXED, __HIP_MEMORY_SCOPE_AGENT));
        }
#pragma unroll
        for (int off = 32; off > 0; off >>= 1)
            acc += __shfl_down(acc, off, 64);
        if (lane == 0) wsum[tid >> 6] = acc;
        __syncthreads();
        if (tid == 0)
            out[0] = (wsum[0] + wsum[1] + wsum[2] + wsum[3]) * (1.0f / B_ITEMS);
    }
}

extern "C" void kernel_launch(void* const* d_in, const int* in_sizes, int n_in,
                              void* d_out, int out_size, void* d_ws, size_t ws_size,
                              hipStream_t stream) {
    const float* pred = (const float*)d_in[0];
    const float* gt   = (const float*)d_in[1];
    const int*   mask = (const int*)  d_in[2];
    const float* fx   = (const float*)d_in[3];
    const float* fy   = (const float*)d_in[4];
    const float* cx   = (const float*)d_in[5];
    const float* cy   = (const float*)d_in[6];
    float* out = (float*)d_out;

    // ws: [0,256) cnt+done | pR 512K | gR 512K | pT 512K | gT 512K | rmG 256K
    char* ws = (char*)d_ws;
    size_t SEG = (size_t)B_ITEMS * N_PTS * 16;
    int*    cnt  = (int*)ws;
    int*    done = cnt + 4;
    float4* pR   = (float4*)(ws + 256);
    float4* gR   = (float4*)(ws + 256 + SEG);
    float4* pT   = (float4*)(ws + 256 + 2 * SEG);
    float4* gT   = (float4*)(ws + 256 + 3 * SEG);
    float*  rmG  = (float*) (ws + 256 + 4 * SEG);

    hipMemsetAsync(cnt, 0, 32, stream);      // cnt[0..3] + done

    prep_kernel<<<dim3(256), 256, 0, stream>>>(
        pred, gt, mask, fx, fy, cx, cy, cnt, pR, gR, pT, gT, rmG, out);

    chamfer_kernel<<<dim3(CH_GRID), 256, 0, stream>>>(
        cnt, pR, gR, pT, gT, rmG, done, out);
}